// Round 7
// baseline (514.377 us; speedup 1.0000x reference)
//
#include <hip/hip_runtime.h>

// ============================================================================
// R9: color-routed owner-records -> deterministic 2-way-bank LDS accumulation.
// R3-R8 invariant: 38.4M LDS atomic f32 adds <-> 218-275us regardless of
// structure => ~230 cy per atomic wave-instr = conflict-serialized RMW
// (64 random lanes -> 32 banks, max-load ~6). R9 routes records so each
// thread owns color c=owner%64: force-add banks collide exactly 2-way and
// each owner is updated by one thread. Front-end: exact count -> parallel
// 3-kernel scan (kills R8's ~100us serial prefix) -> place.
// ============================================================================

#define NBIN   32
#define BA     3200            // atoms per bin (32*3200 = 102400 >= 100000)
#define BF     (BA * 3)        // 9600 floats per bin force/pos slab
#define SEGS   256             // edge segments (count/place blocks)
#define NCOL   64              // colors = owner & 63
#define BPS    (NBIN * NCOL)   // buckets per segment = 2048
#define NBUCK  (SEGS * BPS)    // 524,288 buckets
#define NROW   16              // partial force rows
#define ROW_F  307200          // floats per row (= NBIN * BF)

// ---------------- old fallback path ----------------
#define NBINS      8
#define BIN_ATOMS  12800
#define BIN_F      (BIN_ATOMS * 3)
#define BLOCK      1024
#define MAXCHUNKS  32

typedef __attribute__((ext_vector_type(4))) int ivec4;

__device__ __forceinline__ ivec4 nt_load_i4(const int* p) {
    return __builtin_nontemporal_load((const ivec4*)p);
}
__device__ __forceinline__ void lds_fadd(float* p, float v) {
    __hip_atomic_fetch_add(p, v, __ATOMIC_RELAXED, __HIP_MEMORY_SCOPE_WORKGROUP);
}
__device__ __forceinline__ unsigned lds_uinc(unsigned* p) {
    return __hip_atomic_fetch_add(p, 1u, __ATOMIC_RELAXED, __HIP_MEMORY_SCOPE_WORKGROUP);
}

// ---------------------------------------------------------------------------
// K1: count owner-records per (segment, bin, color) + build pos4.
// ---------------------------------------------------------------------------
__global__ __launch_bounds__(1024) void pf_count(
    const float* __restrict__ pos, float4* __restrict__ pos4,
    const int* __restrict__ src, const int* __restrict__ dst,
    unsigned* __restrict__ cnt, int nEdges, int nAtoms)
{
    __shared__ unsigned h[BPS];
    const int t = threadIdx.x, bid = (int)blockIdx.x;
    h[t] = 0; h[t + 1024] = 0;

    for (int i = bid * 1024 + t; i < nAtoms; i += SEGS * 1024)
        pos4[i] = make_float4(pos[3 * i + 0], pos[3 * i + 1], pos[3 * i + 2], 0.f);
    __syncthreads();

    const int eblk  = ((nEdges + SEGS - 1) / SEGS + 3) & ~3;
    const int ebeg  = bid * eblk;
    const int eend  = (ebeg + eblk < nEdges) ? (ebeg + eblk) : nEdges;
    for (int i4 = (ebeg >> 2) + t; i4 < (eend >> 2); i4 += 1024) {
        const ivec4 s4 = nt_load_i4(src + 4 * i4);
        const ivec4 d4 = nt_load_i4(dst + 4 * i4);
        #pragma unroll
        for (int k = 0; k < 4; ++k) {
            const unsigned su = (unsigned)s4[k], du = (unsigned)d4[k];
            lds_uinc(&h[(su / BA) * NCOL + (su & 63u)]);
            lds_uinc(&h[(du / BA) * NCOL + (du & 63u)]);
        }
    }
    __syncthreads();
    cnt[bid * BPS + t] = h[t];
    cnt[bid * BPS + 1024 + t] = h[t + 1024];
}

// ---------------------------------------------------------------------------
// K2a/b/c: parallel exclusive scan over the 524,288 bucket counts.
// ---------------------------------------------------------------------------
__global__ __launch_bounds__(1024) void pf_scanA(
    const unsigned* __restrict__ cnt, unsigned* __restrict__ bstart,
    unsigned* __restrict__ btot)
{
    __shared__ unsigned wt[16], wo[16];
    const int t = threadIdx.x, lane = t & 63, wv = t >> 6;
    const int gid = (int)blockIdx.x * 1024 + t;
    const unsigned v = cnt[gid];
    unsigned x = v;
    #pragma unroll
    for (int off = 1; off < 64; off <<= 1) {
        const unsigned n = __shfl_up(x, off, 64);
        if (lane >= off) x += n;
    }
    if (lane == 63) wt[wv] = x;
    __syncthreads();
    if (t == 0) {
        unsigned run = 0;
        #pragma unroll
        for (int w = 0; w < 16; ++w) { wo[w] = run; run += wt[w]; }
        btot[blockIdx.x] = run;
    }
    __syncthreads();
    bstart[gid] = (x - v) + wo[wv];
}

__global__ __launch_bounds__(512) void pf_scanB(
    const unsigned* __restrict__ btot, unsigned* __restrict__ boffs)
{
    __shared__ unsigned wt[8], wo[8];
    const int t = threadIdx.x, lane = t & 63, wv = t >> 6;
    const unsigned v = btot[t];
    unsigned x = v;
    #pragma unroll
    for (int off = 1; off < 64; off <<= 1) {
        const unsigned n = __shfl_up(x, off, 64);
        if (lane >= off) x += n;
    }
    if (lane == 63) wt[wv] = x;
    __syncthreads();
    if (t == 0) {
        unsigned run = 0;
        #pragma unroll
        for (int w = 0; w < 8; ++w) { wo[w] = run; run += wt[w]; }
    }
    __syncthreads();
    boffs[t] = (x - v) + wo[wv];
}

__global__ __launch_bounds__(1024) void pf_scanC(
    unsigned* __restrict__ bstart, const unsigned* __restrict__ boffs, int nRec)
{
    const int gid = (int)blockIdx.x * 1024 + threadIdx.x;
    bstart[gid] += boffs[blockIdx.x];
    if (gid == 0) bstart[NBUCK] = (unsigned)nRec;
}

// ---------------------------------------------------------------------------
// K3: place owner-records. rec = local(12b)<<18 | eflag<<17 | other(17b).
// ---------------------------------------------------------------------------
__global__ __launch_bounds__(1024) void pf_place(
    const int* __restrict__ src, const int* __restrict__ dst,
    const unsigned* __restrict__ bstart, unsigned* __restrict__ recs, int nEdges)
{
    __shared__ unsigned cur[BPS];
    const int t = threadIdx.x, bid = (int)blockIdx.x;
    cur[t] = bstart[bid * BPS + t];
    cur[t + 1024] = bstart[bid * BPS + 1024 + t];
    __syncthreads();

    const int eblk  = ((nEdges + SEGS - 1) / SEGS + 3) & ~3;
    const int ebeg  = bid * eblk;
    const int eend  = (ebeg + eblk < nEdges) ? (ebeg + eblk) : nEdges;
    for (int i4 = (ebeg >> 2) + t; i4 < (eend >> 2); i4 += 1024) {
        const ivec4 s4 = nt_load_i4(src + 4 * i4);
        const ivec4 d4 = nt_load_i4(dst + 4 * i4);
        #pragma unroll
        for (int k = 0; k < 4; ++k) {
            const unsigned su = (unsigned)s4[k], du = (unsigned)d4[k];
            const unsigned ob_s = su / BA, ob_d = du / BA;
            const unsigned is = lds_uinc(&cur[ob_s * NCOL + (su & 63u)]);
            recs[is] = ((su - ob_s * BA) << 18) | (1u << 17) | du;
            const unsigned id = lds_uinc(&cur[ob_d * NCOL + (du & 63u)]);
            recs[id] = ((du - ob_d * BA) << 18) | su;
        }
    }
}

// ---------------------------------------------------------------------------
// K4: color-routed accumulation. Block = (obin, SC); 512 threads.
// Thread t handles color t&63 in segs SC*16+(t>>6) and SC*16+8+(t>>6):
// exclusive owner set per thread, LDS add banks collide exactly 2-way.
// LDS: force slab 37.5K | energy 8 | pos slab 37.5K = 75.1 KiB -> 2 blocks/CU.
// ---------------------------------------------------------------------------
__global__ __launch_bounds__(512) void pf_accum3(
    const float* __restrict__ pos, const float4* __restrict__ pos4,
    const float* __restrict__ sigma_p, const float* __restrict__ eps_p,
    const unsigned* __restrict__ recs, const unsigned* __restrict__ bstart,
    float* __restrict__ frep,        // [NROW][ROW_F]
    float* __restrict__ erep,        // [NBIN*NROW]
    int nAtoms)
{
    extern __shared__ float sh[];    // [BF force | 8 energy | BF pos]
    float* sF = sh;
    float* sE = sh + BF;
    float* sP = sh + BF + 8;
    const int t = threadIdx.x, lane = t & 63, wv = t >> 6;
    const int obin = (int)blockIdx.x >> 4;
    const int SC   = (int)blockIdx.x & 15;

    for (int k = t; k < (BF + 8) / 4; k += 512)
        ((float4*)sF)[k] = make_float4(0.f, 0.f, 0.f, 0.f);
    {
        const int aS = obin * BA;
        int nf = nAtoms - aS; if (nf > BA) nf = BA; if (nf < 0) nf = 0; nf *= 3;
        const float* g = pos + (size_t)aS * 3;
        for (int k = t; k < (nf >> 2); k += 512) ((float4*)sP)[k] = ((const float4*)g)[k];
        for (int k = (nf & ~3) + t; k < nf; k += 512) sP[k] = g[k];
    }
    __syncthreads();

    const float sigma = sigma_p[0], eps = eps_p[0];
    const float sig2 = sigma * sigma;
    const float c12 = 12.f * eps, c4 = 4.f * eps;

    float ev = 0.f;
    #pragma unroll
    for (int q = 0; q < 2; ++q) {
        const int seg = SC * 16 + (t >> 6) + q * 8;
        const int bkt = seg * BPS + obin * NCOL + (t & 63);
        const int beg = (int)bstart[bkt];
        const int end = (int)bstart[bkt + 1];

        for (int r = beg; r < end; r += 2) {
            const unsigned rec0 = recs[r];
            const bool v1 = (r + 1) < end;
            const unsigned rec1 = v1 ? recs[r + 1] : 0u;
            const int l0 = rec0 >> 18, o0 = rec0 & 0x1FFFF;
            const int l1 = rec1 >> 18, o1 = rec1 & 0x1FFFF;
            const float4 p0 = pos4[o0];
            const float4 p1 = pos4[o1];
            const float a0x = sP[3 * l0 + 0], a0y = sP[3 * l0 + 1], a0z = sP[3 * l0 + 2];
            const float a1x = sP[3 * l1 + 0], a1y = sP[3 * l1 + 1], a1z = sP[3 * l1 + 2];

            const float d0x = a0x - p0.x, d0y = a0y - p0.y, d0z = a0z - p0.z;
            const float r20  = d0x * d0x + d0y * d0y + d0z * d0z;
            const float ir20 = 1.0f / r20;
            const float s20  = sig2 * ir20;
            const float sr60 = s20 * s20 * s20;
            const float sr120 = sr60 * sr60;
            const float fs0  = c12 * (2.f * sr120 - sr60) * ir20;

            const float d1x = a1x - p1.x, d1y = a1y - p1.y, d1z = a1z - p1.z;
            const float r21  = d1x * d1x + d1y * d1y + d1z * d1z;
            const float ir21 = 1.0f / r21;
            const float s21  = sig2 * ir21;
            const float sr61 = s21 * s21 * s21;
            const float sr121 = sr61 * sr61;
            const float fs1  = c12 * (2.f * sr121 - sr61) * ir21;

            lds_fadd(&sF[3 * l0 + 0], fs0 * d0x);
            lds_fadd(&sF[3 * l0 + 1], fs0 * d0y);
            lds_fadd(&sF[3 * l0 + 2], fs0 * d0z);
            ev += (rec0 & (1u << 17)) ? c4 * (sr120 - sr60) : 0.f;
            if (v1) {
                lds_fadd(&sF[3 * l1 + 0], fs1 * d1x);
                lds_fadd(&sF[3 * l1 + 1], fs1 * d1y);
                lds_fadd(&sF[3 * l1 + 2], fs1 * d1z);
                ev += (rec1 & (1u << 17)) ? c4 * (sr121 - sr61) : 0.f;
            }
        }
    }

    #pragma unroll
    for (int off = 32; off > 0; off >>= 1) ev += __shfl_down(ev, off, 64);
    if (lane == 0) sE[wv] = ev;
    __syncthreads();

    float4* d = (float4*)(frep + (size_t)SC * ROW_F + (size_t)obin * BF);
    for (int k = t; k < BF / 4; k += 512) d[k] = ((const float4*)sF)[k];
    if (t == 0) {
        float e = 0.f;
        #pragma unroll
        for (int w = 0; w < 8; ++w) e += sE[w];
        erep[blockIdx.x] = e;
    }
}

// ---------------------------------------------------------------------------
// Reduce (rows -> output).
// ---------------------------------------------------------------------------
__global__ __launch_bounds__(256) void pairforce_reduce(
    const float* __restrict__ frep,
    const float* __restrict__ erep,
    float* __restrict__ out, int n3, int nChunks, int nPart)
{
    const int i = blockIdx.x * 256 + threadIdx.x;
    if (i < n3) {
        float acc = 0.f;
        for (int c = 0; c < nChunks; ++c)
            acc += frep[(size_t)c * ROW_F + i];
        out[1 + i] = acc;
    }
    if (blockIdx.x == gridDim.x - 1) {
        float e = 0.f;
        for (int jj = threadIdx.x; jj < nPart; jj += 256) e += erep[jj];
        #pragma unroll
        for (int off = 32; off > 0; off >>= 1) e += __shfl_down(e, off, 64);
        __shared__ float ep[4];
        if ((threadIdx.x & 63) == 0) ep[threadIdx.x >> 6] = e;
        __syncthreads();
        if (threadIdx.x == 0) out[0] = ep[0] + ep[1] + ep[2] + ep[3];
    }
}

// ---------------------------------------------------------------------------
// Fallback: R3's binned kernel, verbatim.
// ---------------------------------------------------------------------------
__global__ __launch_bounds__(BLOCK, 1) void pairforce_binned(
    const float* __restrict__ pos,
    const float* __restrict__ sigma_p,
    const float* __restrict__ eps_p,
    const int*   __restrict__ src,
    const int*   __restrict__ dst,
    float* __restrict__ frep,
    float* __restrict__ erep,
    int nEdges, int chunkEdges)
{
    extern __shared__ float sh[];
    const int t = threadIdx.x;
    const int b = blockIdx.x % NBINS;
    const int c = blockIdx.x / NBINS;

    for (int jj = t; jj < (BIN_F + 16) / 4; jj += BLOCK)
        ((float4*)sh)[jj] = make_float4(0.f, 0.f, 0.f, 0.f);
    __syncthreads();

    const float sigma = sigma_p[0];
    const float eps   = eps_p[0];
    const float sig2  = sigma * sigma;
    const int binStart = b * BIN_ATOMS;

    const int start = c * chunkEdges;
    const int end   = min(start + chunkEdges, nEdges);

    const int4* src4 = (const int4*)src;
    const int4* dst4 = (const int4*)dst;

    float ev = 0.0f;

    for (int i4 = (start >> 2) + t; i4 < (end >> 2); i4 += BLOCK) {
        const int4 s4 = src4[i4];
        const int4 d4 = dst4[i4];
        #pragma unroll
        for (int k = 0; k < 4; ++k) {
            const int s = (k == 0) ? s4.x : (k == 1) ? s4.y : (k == 2) ? s4.z : s4.w;
            const int d = (k == 0) ? d4.x : (k == 1) ? d4.y : (k == 2) ? d4.z : d4.w;
            const unsigned ls = (unsigned)(s - binStart);
            const unsigned ld = (unsigned)(d - binStart);
            const bool hs = ls < BIN_ATOMS;
            const bool hd = ld < BIN_ATOMS;
            if (hs | hd) {
                const float dx = pos[3 * s + 0] - pos[3 * d + 0];
                const float dy = pos[3 * s + 1] - pos[3 * d + 1];
                const float dz = pos[3 * s + 2] - pos[3 * d + 2];
                const float r2     = dx * dx + dy * dy + dz * dz;
                const float inv_r2 = 1.0f / r2;
                const float s2     = sig2 * inv_r2;
                const float sr6    = s2 * s2 * s2;
                const float sr12   = sr6 * sr6;
                const float fs = 12.0f * eps * (2.0f * sr12 - sr6) * inv_r2;
                const float fx = fs * dx;
                const float fy = fs * dy;
                const float fz = fs * dz;
                if (hs) {
                    atomicAdd(&sh[3 * ls + 0],  fx);
                    atomicAdd(&sh[3 * ls + 1],  fy);
                    atomicAdd(&sh[3 * ls + 2],  fz);
                    ev += 4.0f * eps * (sr12 - sr6);
                }
                if (hd) {
                    atomicAdd(&sh[3 * ld + 0], -fx);
                    atomicAdd(&sh[3 * ld + 1], -fy);
                    atomicAdd(&sh[3 * ld + 2], -fz);
                }
            }
        }
    }

    #pragma unroll
    for (int off = 32; off > 0; off >>= 1)
        ev += __shfl_down(ev, off, 64);
    if ((t & 63) == 0) sh[BIN_F + (t >> 6)] = ev;
    __syncthreads();

    float4* outSeg = (float4*)(frep + (size_t)c * ROW_F + (size_t)b * BIN_F);
    for (int jj = t; jj < BIN_F / 4; jj += BLOCK)
        outSeg[jj] = ((float4*)sh)[jj];

    if (t == 0) {
        float e = 0.f;
        #pragma unroll
        for (int w = 0; w < 16; ++w) e += sh[BIN_F + w];
        erep[blockIdx.x] = e;
    }
}

extern "C" void kernel_launch(void* const* d_in, const int* in_sizes, int n_in,
                              void* d_out, int out_size, void* d_ws, size_t ws_size,
                              hipStream_t stream)
{
    const float* pos     = (const float*)d_in[0];
    const float* sigma_p = (const float*)d_in[1];
    const float* eps_p   = (const float*)d_in[2];
    const int*   edge    = (const int*)d_in[3];

    const int nEdges = in_sizes[3] / 2;      // edge_index is [2, E]
    const int* src = edge;
    const int* dst = edge + nEdges;

    const int n3 = out_size - 1;             // 3*N
    const int nAtoms = n3 / 3;
    const int nRec = 2 * nEdges;

    // ---- workspace layout (~77 MB; 88.5 MB proven available in R4/R5) ----
    auto alignup = [](size_t x) { return (x + 255) & ~(size_t)255; };
    size_t off = 0;
    unsigned* recs   = (unsigned*)((char*)d_ws + off); off = alignup(off + (size_t)nRec * 4);
    unsigned* cntp   = (unsigned*)((char*)d_ws + off); off = alignup(off + (size_t)NBUCK * 4);
    unsigned* bstart = (unsigned*)((char*)d_ws + off); off = alignup(off + (size_t)(NBUCK + 1) * 4);
    unsigned* btot   = (unsigned*)((char*)d_ws + off); off = alignup(off + 512 * 4);
    unsigned* boffs  = (unsigned*)((char*)d_ws + off); off = alignup(off + 512 * 4);
    float*    pos4   = (float*)((char*)d_ws + off);    off = alignup(off + (size_t)(NBIN * BA) * 16);
    float*    frepN  = (float*)((char*)d_ws + off);    off = alignup(off + (size_t)NROW * ROW_F * 4);
    float*    erepN  = (float*)((char*)d_ws + off);    off = alignup(off + (size_t)(NBIN * NROW) * 4);

    if (ws_size >= off && nAtoms <= NBIN * BA && nEdges > 0 && (nEdges & 3) == 0) {
        pf_count<<<SEGS, 1024, 0, stream>>>(pos, (float4*)pos4, src, dst,
                                            cntp, nEdges, nAtoms);
        pf_scanA<<<NBUCK / 1024, 1024, 0, stream>>>(cntp, bstart, btot);
        pf_scanB<<<1, 512, 0, stream>>>(btot, boffs);
        pf_scanC<<<NBUCK / 1024, 1024, 0, stream>>>(bstart, boffs, nRec);
        pf_place<<<SEGS, 1024, 0, stream>>>(src, dst, bstart, recs, nEdges);
        const size_t shb = (size_t)(2 * BF + 8) * sizeof(float);   // 76,832 B
        pf_accum3<<<NBIN * NROW, 512, shb, stream>>>(pos, (const float4*)pos4,
                                                     sigma_p, eps_p, recs, bstart,
                                                     frepN, erepN, nAtoms);
        pairforce_reduce<<<(n3 + 255) / 256, 256, 0, stream>>>(
            frepN, erepN, (float*)d_out, n3, NROW, NBIN * NROW);
        return;
    }

    // ---- fallback: R3 path ----
    const size_t rowBytes = (size_t)ROW_F * sizeof(float);
    int nChunks = (int)((ws_size - 4096) / rowBytes);
    if (nChunks > MAXCHUNKS) nChunks = MAXCHUNKS;
    if (nChunks < 1) nChunks = 1;

    const int chunkEdges = (((nEdges + nChunks - 1) / nChunks) + 3) & ~3;

    float* frep = (float*)d_ws;
    float* erep = frep + (size_t)nChunks * ROW_F;

    const size_t shbytes = (size_t)(BIN_F + 16) * sizeof(float);

    const int grid1 = nChunks * NBINS;
    pairforce_binned<<<grid1, BLOCK, shbytes, stream>>>(
        pos, sigma_p, eps_p, src, dst, frep, erep, nEdges, chunkEdges);

    const int grid2 = (n3 + 255) / 256;
    pairforce_reduce<<<grid2, 256, 0, stream>>>(
        frep, erep, (float*)d_out, n3, nChunks, nChunks * NBINS);
}